// Round 1
// baseline (153.117 us; speedup 1.0000x reference)
//
#include <hip/hip_runtime.h>

// GroupKAN: B=131072 rows, F=64 in-features, G=8 groups x GS=8, NB=16 RBF
// centers, O=64 outputs/group -> 512 out-features, then BatchNorm over batch.
// indices == arange(64).reshape(8,8) -> pure reshape, no gather needed.

#define B_ROWS 131072
#define NFEAT  64
#define NGRP   8
#define GSZ    8
#define NBAS   16
#define NJ     512          // G*O output features
#define BN_EPS 1e-5f

#define CHUNK  8            // rows staged in LDS per phase
#define NBLOCKS 1024
#define ROWS_PER_BLOCK (B_ROWS / NBLOCKS)   // 128

// ws layout (floats): [0:512) sums, [512:1024) sumsq, [1024:1536) scale,
// [1536:2048) shift
template <int PASS>
__global__ __launch_bounds__(512)
void kan_pass(const float* __restrict__ x,
              const float* __restrict__ centres,
              const float* __restrict__ log_widths,
              const float* __restrict__ rbf_w,
              const float* __restrict__ lin_w,
              const float* __restrict__ proj_w,
              const float* __restrict__ proj_b,
              float* __restrict__ ws,
              float* __restrict__ out)
{
    __shared__ float s_rbf[2][CHUNK][NFEAT];

    const int t  = threadIdx.x;
    const int r  = t >> 6;        // phase A: row within chunk (0..7)
    const int c  = t & 63;        // phase A: input column (0..63)
    const int gc = c >> 3;        // group of this column
    const int g  = t >> 6;        // phase B: output group (0..7)

    // RBF params for column-group gc, in registers (loaded once, L2-served)
    float cc[NBAS], is[NBAS], w[NBAS];
#pragma unroll
    for (int nb = 0; nb < NBAS; ++nb) {
        cc[nb] = centres[gc * NBAS + nb];
        is[nb] = 1.0f / (__expf(log_widths[gc * NBAS + nb]) + 1e-6f);
        w[nb]  = rbf_w[gc * NBAS + nb];
    }
    const float lw = lin_w[gc];

    // projection weights for output feature j = t (g = t>>6, o = t&63)
    float pw[GSZ];
#pragma unroll
    for (int s = 0; s < GSZ; ++s) pw[s] = proj_w[t * GSZ + s];
    const float pb = proj_b[t];

    float scale = 0.0f, shift = 0.0f;
    if (PASS == 1) { scale = ws[1024 + t]; shift = ws[1536 + t]; }

    float fsum = 0.0f, fsq = 0.0f;
    const int row0 = blockIdx.x * ROWS_PER_BLOCK;

    for (int ch = 0; ch < ROWS_PER_BLOCK / CHUNK; ++ch) {
        const int buf = ch & 1;
        const int b   = row0 + ch * CHUNK + r;

        // ---- phase A: rbf_out(b, c) -> LDS ----
        const float xv  = x[b * NFEAT + c];     // 256B/wave coalesced
        float acc = lw * xv;
#pragma unroll
        for (int nb = 0; nb < NBAS; ++nb) {
            const float d = (xv - cc[nb]) * is[nb];
            acc += w[nb] * __expf(-0.5f * d * d);
        }
        s_rbf[buf][r][c] = acc;                 // 2-way bank alias: free

        __syncthreads();   // one barrier/chunk; dbuf protects prior readers

        // ---- phase B: proj for feature j = t over 8 rows ----
#pragma unroll
        for (int rr = 0; rr < CHUNK; ++rr) {
            // all 64 lanes of this wave read the same addresses: broadcast
            const float4 v0 = *reinterpret_cast<const float4*>(&s_rbf[buf][rr][g * GSZ]);
            const float4 v1 = *reinterpret_cast<const float4*>(&s_rbf[buf][rr][g * GSZ + 4]);
            float p = pb;
            p += v0.x * pw[0] + v0.y * pw[1] + v0.z * pw[2] + v0.w * pw[3];
            p += v1.x * pw[4] + v1.y * pw[5] + v1.z * pw[6] + v1.w * pw[7];
            if (PASS == 0) {
                fsum += p;
                fsq  += p * p;
            } else {
                out[(size_t)(row0 + ch * CHUNK + rr) * NJ + t] = p * scale + shift;
            }
        }
    }

    if (PASS == 0) {
        atomicAdd(&ws[t],       fsum);
        atomicAdd(&ws[512 + t], fsq);
    }
}

__global__ __launch_bounds__(512)
void kan_finalize(const float* __restrict__ bn_gamma,
                  const float* __restrict__ bn_beta,
                  float* __restrict__ ws)
{
    const int j = threadIdx.x;
    const float inv_b = 1.0f / (float)B_ROWS;
    const float mean  = ws[j] * inv_b;
    float var = ws[512 + j] * inv_b - mean * mean;
    var = fmaxf(var, 0.0f);
    const float sc = bn_gamma[j] * rsqrtf(var + BN_EPS);
    ws[1024 + j] = sc;
    ws[1536 + j] = bn_beta[j] - mean * sc;
}

extern "C" void kernel_launch(void* const* d_in, const int* in_sizes, int n_in,
                              void* d_out, int out_size, void* d_ws, size_t ws_size,
                              hipStream_t stream)
{
    const float* x           = (const float*)d_in[0];
    const float* centres     = (const float*)d_in[1];
    const float* log_widths  = (const float*)d_in[2];
    const float* rbf_weights = (const float*)d_in[3];
    const float* linear_w    = (const float*)d_in[4];
    const float* proj_w      = (const float*)d_in[5];
    const float* proj_b      = (const float*)d_in[6];
    const float* bn_gamma    = (const float*)d_in[7];
    const float* bn_beta     = (const float*)d_in[8];
    // d_in[9] = indices: identity arange(64) reshape -> not needed

    float* ws  = (float*)d_ws;
    float* out = (float*)d_out;

    // zero the sum/sumsq accumulators (first 1024 floats)
    hipMemsetAsync(ws, 0, 1024 * sizeof(float), stream);

    kan_pass<0><<<NBLOCKS, 512, 0, stream>>>(x, centres, log_widths, rbf_weights,
                                             linear_w, proj_w, proj_b, ws, out);
    kan_finalize<<<1, 512, 0, stream>>>(bn_gamma, bn_beta, ws);
    kan_pass<1><<<NBLOCKS, 512, 0, stream>>>(x, centres, log_widths, rbf_weights,
                                             linear_w, proj_w, proj_b, ws, out);
}